// Round 5
// baseline (383.539 us; speedup 1.0000x reference)
//
#include <hip/hip_runtime.h>

// Problem constants (B,S,D,H,HD) = (4,1024,1024,16,64)
#define B_ 4
#define S_ 1024
#define D_ 1024
#define H_ 16
#define E_ 64
#define BS_ (B_*S_)
#define BHSE_ (B_*H_*S_*E_)   // 4,194,304

typedef __attribute__((ext_vector_type(8))) short bf16x8;   // 8 bf16 in 4 VGPRs
typedef __attribute__((ext_vector_type(4))) float f32x4;

__device__ __forceinline__ unsigned short f2bf(float f) {
    unsigned int x = __float_as_uint(f);
    x = (x + 0x7FFFu + ((x >> 16) & 1u)) >> 16;   // RNE
    return (unsigned short)x;
}
__device__ __forceinline__ float bf2f(unsigned short u) {
    return __uint_as_float(((unsigned int)u) << 16);
}
__device__ __forceinline__ float ldin(const void* p, size_t i, int isb) {
    return isb ? bf2f(((const unsigned short*)p)[i]) : ((const float*)p)[i];
}

// 2^x : v_exp_f32 is natively base-2
#if __has_builtin(__builtin_amdgcn_exp2f)
#define EXP2(x) __builtin_amdgcn_exp2f(x)
#else
#define EXP2(x) __expf((x) * 0.6931471805599453f)
#endif

// async global->LDS, 16B per lane; LDS dest = wave-uniform base + lane*16
__device__ __forceinline__ void gl2lds16(const void* g, void* l) {
    __builtin_amdgcn_global_load_lds(
        (const __attribute__((address_space(1))) void*)g,
        (__attribute__((address_space(3))) void*)l, 16, 0, 0);
}

// ---------------------------------------------------------------------------
// Kernel 0: detect input dtype (1=bf16, 0=fp32) -- see R0 notes.
// ---------------------------------------------------------------------------
__global__ void detect_dtype(const unsigned int* q, int* flag) {
    __shared__ int cnt;
    if (threadIdx.x == 0) cnt = 0;
    __syncthreads();
    unsigned int w = q[threadIdx.x];
    unsigned int lo = w & 0xFFFFu;
    unsigned int e = (lo >> 7) & 0xFFu;
    int ok = (lo == 0u) || (e >= 100u && e <= 145u);
    atomicAdd(&cnt, ok);
    __syncthreads();
    if (threadIdx.x == 0) flag[0] = (cnt >= 240) ? 1 : 0;
}

// ---------------------------------------------------------------------------
// Kernel 1: weight permutes via LDS-transposed 64x64 tiles (both directions
// coalesced). z=0..2: W{q,k,v}[h][d][e] -> WT[z][(h*64+e)][d];
// z=3: Wo[d][o] -> WT[3][o][d].
// ---------------------------------------------------------------------------
__global__ __launch_bounds__(256) void conv_w2(
        const void* Wq, const void* Wk, const void* Wv, const void* Wo,
        const void* bq_, const void* bk_, const void* bv_, const void* bo_,
        unsigned short* WT, float* biases, const int* flag) {
    __shared__ unsigned short Tt[64][72];
    const int isb = flag[0];
    const int z = blockIdx.z, t = threadIdx.x;
    const void* src = (z == 0) ? Wq : (z == 1) ? Wk : (z == 2) ? Wv : Wo;
    const int r0 = blockIdx.y * 64;          // d-tile origin
    const int c0 = blockIdx.x;               // head (z<3) or o-tile (z=3)
    {
        int dl = t >> 2, qc = t & 3;
        size_t base;
        if (z < 3) base = (size_t)c0 * 65536 + (size_t)(r0 + dl) * 64 + qc * 16;
        else       base = (size_t)(r0 + dl) * 1024 + (size_t)c0 * 64 + qc * 16;
        if (isb) {
            const unsigned short* s = (const unsigned short*)src + base;
            bf16x8 a0 = *(const bf16x8*)s, a1 = *(const bf16x8*)(s + 8);
#pragma unroll
            for (int j = 0; j < 8; j++) {
                Tt[qc * 16 + j][dl] = (unsigned short)a0[j];
                Tt[qc * 16 + 8 + j][dl] = (unsigned short)a1[j];
            }
        } else {
            const float* s = (const float*)src + base;
#pragma unroll
            for (int j = 0; j < 16; j++) Tt[qc * 16 + j][dl] = f2bf(s[j]);
        }
    }
    __syncthreads();
    {
        int el = t >> 2, qc = t & 3;
        size_t dst = (size_t)z * D_ * D_ + (size_t)(c0 * 64 + el) * D_ + r0 + qc * 16;
        *(bf16x8*)&WT[dst]     = *(const bf16x8*)&Tt[el][qc * 16];
        *(bf16x8*)&WT[dst + 8] = *(const bf16x8*)&Tt[el][qc * 16 + 8];
    }
    if (z == 3 && blockIdx.y == 0 && blockIdx.x < 4) {
        const void* bs = (blockIdx.x == 0) ? bq_ : (blockIdx.x == 1) ? bk_
                       : (blockIdx.x == 2) ? bv_ : bo_;
#pragma unroll
        for (int j = 0; j < 4; j++) {
            int i = t * 4 + j;
            biases[blockIdx.x * 1024 + i] = ldin(bs, i, isb);
        }
    }
}

// ---------------------------------------------------------------------------
// Kernel 2: mask bitpack, transposed: packT[b][kt][s] bit k = mask[b][s][kt*64+k]
// ---------------------------------------------------------------------------
__global__ void maskpack(const int* mask, unsigned long long* packT) {
    int W = blockIdx.x * 4 + (threadIdx.x >> 6);    // 0..65535
    int lane = threadIdx.x & 63;
    int b = W >> 14, rem = W & 16383, s = rem >> 4, kt = rem & 15;
    int mv = mask[((size_t)b * 1024 + s) * 1024 + kt * 64 + lane];
    unsigned long long bits = __ballot(mv != 0);
    if (lane == 0) packT[((size_t)b * 16 + kt) * 1024 + s] = bits;
}

// ---------------------------------------------------------------------------
// Kernel 3 (R5): bf16 MFMA GEMM. BK=64 (16 iters, half the barrier drains),
// XOR-swizzled LDS (fragment reads 2-way max = free), XCD-aware 1-D block
// remap: xcd=lid&7 owns a disjoint m-band per z => A fetched once chip-wide,
// B once per XCD (logical fill 384 -> ~72 MB).
// MODE 0: 3 projections (z: Q,K -> [b][h][s][e]; V -> [b][h][e][s]).
// MODE 1: final GEMM (A=heads bf16), writes d_out per dtype flag.
// ---------------------------------------------------------------------------
template<int BM, int MODE>
__global__ __launch_bounds__(256) void gemm_k(
        const void* A0, const void* A1, const void* A2,
        const unsigned short* BtB, const float* biasB, void* dstB, const int* flag) {
    constexpr int BK = 64;                       // ushorts per row
    constexpr int TOT16 = (BM + 128) * BK;       // LDS ushorts: [A BMxBK | B 128xBK]
    constexpr int CALLS = TOT16 / 512;           // 1KB chunks (8 rows x 64 cols)
    constexpr int CPW = CALLS / 4;
    constexpr int MT = BM / 32;
    __shared__ unsigned short buf[TOT16];

    const int t = threadIdx.x, lane = t & 63, w = t >> 6;
    const int lm = lane & 15, q4 = lane >> 4;
    const int wm = w >> 1, wn = w & 1;
    const int lr = lane >> 3, lg = (lane & 7) ^ lr;   // DMA row-in-chunk, src granule
    const int fl = flag[0];

    // ---- XCD-aware swizzled decode (heuristic: linear id % 8 = XCD) ----
    const int lid = blockIdx.x;
    int m0, n0, z = 0;
    if (MODE == 0) {
        int x = lid & 7, slot = lid >> 3;        // slot in [0,96)
        z = slot >> 5;                            // 0..2
        int s32 = slot & 31;
        int n = s32 & 7, mi = s32 >> 3;           // mi in [0,4)
        m0 = (x * 4 + mi) * BM;                   // 32 m-tiles total
        n0 = n * 128;
    } else {
        int x = lid & 7, slot = lid >> 3;         // slot in [0,64)
        int n = slot & 7, mi = slot >> 3;         // mi in [0,8)
        m0 = (x * 8 + mi) * BM;                   // 64 m-tiles total
        n0 = n * 128;
    }

    const void* A; const unsigned short* Bt; const float* bias;
    int aisb;
    if (MODE == 0) {
        A = (z == 0) ? A0 : (z == 1 ? A1 : A2);
        Bt = BtB + (size_t)z * D_ * D_;
        bias = biasB + z * 1024;
        aisb = fl;
    } else {
        A = A0; Bt = BtB; bias = biasB; aisb = 1;
    }

    f32x4 acc[MT][4];
#pragma unroll
    for (int i = 0; i < MT; i++)
#pragma unroll
        for (int j = 0; j < 4; j++) acc[i][j] = (f32x4){0.f, 0.f, 0.f, 0.f};

    for (int kk = 0; kk < D_; kk += BK) {
        __syncthreads();                          // prior frag reads done
        // chunk c: LDS rows c*8..c*8+7; lane -> row c*8+lr, LDS slot (lane&7),
        // global granule lg = (lane&7)^lr  => LDS slot s of row r holds
        // global granule s ^ (r&7).
        if (aisb) {
#pragma unroll
            for (int i = 0; i < CPW; ++i) {
                int c = w * CPW + i;
                int lrow = c * 8 + lr;
                const unsigned short* g;
                if (lrow < BM)
                    g = (const unsigned short*)A + (size_t)(m0 + lrow) * D_ + kk + lg * 8;
                else
                    g = Bt + (size_t)(n0 + lrow - BM) * D_ + kk + lg * 8;
                gl2lds16(g, buf + c * 512);
            }
        } else {
            // fp32 A path: convert via regs into the same swizzled layout
#pragma unroll
            for (int i = 0; i < CPW; ++i) {
                int c = w * CPW + i;
                int lrow = c * 8 + lr;
                if (lrow < BM) {
                    const float* af = (const float*)A + (size_t)(m0 + lrow) * D_ + kk + lg * 8;
                    bf16x8 v;
#pragma unroll
                    for (int jj = 0; jj < 8; jj++) v[jj] = (short)f2bf(af[jj]);
                    *(bf16x8*)(buf + c * 512 + (lane & 7) * 8 + lr * 64) = v;
                } else {
                    gl2lds16(Bt + (size_t)(n0 + lrow - BM) * D_ + kk + lg * 8,
                             buf + c * 512);
                }
            }
        }
        __syncthreads();                          // drains vmcnt+lgkmcnt

        const unsigned short* As = buf;
        const unsigned short* Bs = buf + BM * BK;
#pragma unroll
        for (int kh = 0; kh < 2; ++kh) {          // two K=32 halves of BK=64
            bf16x8 af[MT], bv[4];
#pragma unroll
            for (int mt = 0; mt < MT; mt++) {
                int row = wm * (BM / 2) + mt * 16 + lm;
                int gr = (kh * 4 + q4) ^ (row & 7);
                af[mt] = *(const bf16x8*)&As[row * 64 + gr * 8];
            }
#pragma unroll
            for (int nt = 0; nt < 4; nt++) {
                int row = wn * 64 + nt * 16 + lm;
                int gr = (kh * 4 + q4) ^ (row & 7);
                bv[nt] = *(const bf16x8*)&Bs[row * 64 + gr * 8];
            }
#pragma unroll
            for (int mt = 0; mt < MT; mt++)
#pragma unroll
                for (int nt = 0; nt < 4; nt++)
                    acc[mt][nt] = __builtin_amdgcn_mfma_f32_16x16x32_bf16(
                        af[mt], bv[nt], acc[mt][nt], 0, 0, 0);
        }
    }

    // epilogue: C/D layout col=lane&15, row=(lane>>4)*4+reg
#pragma unroll
    for (int mt = 0; mt < MT; mt++)
#pragma unroll
        for (int nt = 0; nt < 4; nt++)
#pragma unroll
            for (int r = 0; r < 4; r++) {
                int M = m0 + wm * (BM / 2) + mt * 16 + q4 * 4 + r;
                int N = n0 + wn * 64 + nt * 16 + lm;
                float v = acc[mt][nt][r] + bias[N];
                if (MODE == 0) {
                    int bb = M >> 10, s = M & 1023, hh = N >> 6, e = N & 63;
                    unsigned short* d16 = (unsigned short*)dstB + (size_t)z * BHSE_;
                    if (z < 2)
                        d16[((size_t)(bb * H_ + hh) * S_ + s) * E_ + e] = f2bf(v);
                    else
                        d16[((size_t)(bb * H_ + hh) * E_ + e) * S_ + s] = f2bf(v);
                } else {
                    size_t idx = (size_t)M * D_ + N;
                    if (fl) ((unsigned short*)dstB)[idx] = f2bf(v);
                    else    ((float*)dstB)[idx] = v;
                }
            }
}

// ---------------------------------------------------------------------------
// Kernel 4: fused attention (R4 structure: LDS double-buffered K/V DMA tiles,
// XOR swizzle, base-2 softmax) + R5 XCD remap: all 16 q-tiles of one (b,h)
// land on one XCD => K/V fetched once per XCD (8 (b,h) pairs -> 2MB L2 set).
// ---------------------------------------------------------------------------
#define PSTR 88
__global__ __launch_bounds__(256) void attn64(
        const unsigned short* Qp, const unsigned short* Kp, const unsigned short* VpT,
        const unsigned long long* packT, unsigned short* heads) {
    __shared__ unsigned short KT[2][4096];   // [buf][64 keys x 64 e], swizzled
    __shared__ unsigned short VT[2][4096];   // [buf][64 e x 64 keys], swizzled
    __shared__ unsigned short Pw[4][16 * PSTR];

    // XCD-aware decode: lid&7 = XCD; each XCD owns 8 (b,h) pairs complete.
    const int lid = blockIdx.x;
    const int x = lid & 7, slot = lid >> 3;       // slot in [0,128)
    const int hb = x * 8 + (slot >> 4);           // (b*16+h) in [0,64)
    const int qt = slot & 15;
    const int b = hb >> 4, h = hb & 15;

    const int t = threadIdx.x, w = t >> 6, lane = t & 63, lm = lane & 15, q4 = lane >> 4;
    const size_t bh = ((size_t)b * H_ + h) * S_ * E_;
    const unsigned short* Qb = Qp + bh;
    const unsigned short* Kb = Kp + bh;
    const unsigned short* Vb = VpT + bh;                // Vb[e*1024 + s]
    const int q0 = qt * 64 + w * 16;
    unsigned short* P = &Pw[w][0];

    // per-lane invariant DMA source offsets (ushort units)
    const int l3 = lane >> 3, l7 = lane & 7;
    const int kLaneOff = l3 * 64 + (l7 ^ l3) * 8;       // within an 8-row K chunk
    const int vLaneOff = l3 * 1024 + (l7 ^ l3) * 8;     // within an 8-row V chunk

    // swizzled LDS fragment chunk indices (granule = 8 ushorts)
    const int sw = lm & 7;
    const int c0 = (q4 ^ sw) * 8, c1 = ((q4 ^ 4) ^ sw) * 8;

    // Q B-fragments, held for the whole sweep
    bf16x8 bq0 = *(const bf16x8*)&Qb[(size_t)(q0 + lm) * E_ + q4 * 8];
    bf16x8 bq1 = *(const bf16x8*)&Qb[(size_t)(q0 + lm) * E_ + 32 + q4 * 8];

    f32x4 oacc[4];
#pragma unroll
    for (int i = 0; i < 4; i++) oacc[i] = (f32x4){0.f, 0.f, 0.f, 0.f};
    float mrun = -3.0e38f, lrun = 0.f;
    const float scale2 = 0.03125f * 1.4426950408889634f;   // log2e / sqrt(D)

#define STAGE(ktile, bufi)                                                    \
    {                                                                         \
        int k0s = (ktile) * 64;                                               \
        _Pragma("unroll")                                                     \
        for (int i_ = 0; i_ < 4; ++i_) {                                      \
            int c_ = w * 4 + i_;                                              \
            if (c_ < 8) {                                                     \
                gl2lds16(Kb + (size_t)k0s * 64 + c_ * 512 + kLaneOff,         \
                         &KT[bufi][c_ * 512]);                                \
            } else {                                                          \
                int cc_ = c_ - 8;                                             \
                gl2lds16(Vb + (size_t)cc_ * 8192 + k0s + vLaneOff,            \
                         &VT[bufi][cc_ * 512]);                               \
            }                                                                 \
        }                                                                     \
    }

    STAGE(0, 0)

    for (int kt = 0; kt < S_ / 64; ++kt) {
        const int bufi = kt & 1;
        __syncthreads();                 // own-vmcnt drain + barrier: tile kt ready
        if (kt < 15) STAGE(kt + 1, bufi ^ 1)

        unsigned long long mk = packT[((size_t)b * 16 + kt) * 1024 + q0 + lm];

        // Sc^T from LDS K tile
        f32x4 st[4];
#pragma unroll
        for (int jt = 0; jt < 4; ++jt) {
            const unsigned short* kr = &KT[bufi][(jt * 16 + lm) * 64];
            bf16x8 ka0 = *(const bf16x8*)&kr[c0];
            bf16x8 ka1 = *(const bf16x8*)&kr[c1];
            f32x4 zz = (f32x4){0.f, 0.f, 0.f, 0.f};
            zz = __builtin_amdgcn_mfma_f32_16x16x32_bf16(ka0, bq0, zz, 0, 0, 0);
            zz = __builtin_amdgcn_mfma_f32_16x16x32_bf16(ka1, bq1, zz, 0, 0, 0);
            st[jt] = zz;
        }
        float sv[4][4];
        float tmx = -3.0e38f;
#pragma unroll
        for (int jt = 0; jt < 4; ++jt)
#pragma unroll
            for (int r = 0; r < 4; r++) {
                int kb = jt * 16 + q4 * 4 + r;
                float xm = ((mk >> kb) & 1ull) ? st[jt][r] * scale2 : -3.0e38f;
                sv[jt][r] = xm;
                tmx = fmaxf(tmx, xm);
            }
        tmx = fmaxf(tmx, __shfl_xor(tmx, 16, 64));
        tmx = fmaxf(tmx, __shfl_xor(tmx, 32, 64));
        float mnew = fmaxf(mrun, tmx);
        float alpha = EXP2(mrun - mnew);
        float ssum = 0.f;
        unsigned long long pk[4];
#pragma unroll
        for (int jt = 0; jt < 4; ++jt) {
            float p0 = EXP2(sv[jt][0] - mnew);
            float p1 = EXP2(sv[jt][1] - mnew);
            float p2 = EXP2(sv[jt][2] - mnew);
            float p3 = EXP2(sv[jt][3] - mnew);
            ssum += (p0 + p1) + (p2 + p3);
            pk[jt] = (unsigned long long)f2bf(p0)
                   | ((unsigned long long)f2bf(p1) << 16)
                   | ((unsigned long long)f2bf(p2) << 32)
                   | ((unsigned long long)f2bf(p3) << 48);
        }
        ssum += __shfl_xor(ssum, 16, 64);
        ssum += __shfl_xor(ssum, 32, 64);
        lrun = lrun * alpha + ssum;
        mrun = mnew;
#pragma unroll
        for (int nt = 0; nt < 4; nt++) oacc[nt] = oacc[nt] * alpha;

        // P C->B layout via per-wave LDS (in-order DS pipe, no barrier)
#pragma unroll
        for (int jt = 0; jt < 4; ++jt)
            *(unsigned long long*)&P[lm * PSTR + jt * 16 + q4 * 4] = pk[jt];
        bf16x8 bp0 = *(const bf16x8*)&P[lm * PSTR + q4 * 8];
        bf16x8 bp1 = *(const bf16x8*)&P[lm * PSTR + 32 + q4 * 8];

        // PV from LDS V tile
#pragma unroll
        for (int nt = 0; nt < 4; nt++) {
            const unsigned short* vr = &VT[bufi][(nt * 16 + lm) * 64];
            bf16x8 va0 = *(const bf16x8*)&vr[c0];
            bf16x8 va1 = *(const bf16x8*)&vr[c1];
            oacc[nt] = __builtin_amdgcn_mfma_f32_16x16x32_bf16(va0, bp0, oacc[nt], 0, 0, 0);
            oacc[nt] = __builtin_amdgcn_mfma_f32_16x16x32_bf16(va1, bp1, oacc[nt], 0, 0, 0);
        }
    }

    float inv = 1.0f / lrun;
#pragma unroll
    for (int nt = 0; nt < 4; nt++) {
        unsigned long long hv =
              (unsigned long long)f2bf(oacc[nt][0] * inv)
            | ((unsigned long long)f2bf(oacc[nt][1] * inv) << 16)
            | ((unsigned long long)f2bf(oacc[nt][2] * inv) << 32)
            | ((unsigned long long)f2bf(oacc[nt][3] * inv) << 48);
        *(unsigned long long*)&heads[(size_t)(b * S_ + q0 + lm) * D_ + h * E_ + nt * 16 + q4 * 4] = hv;
    }
}

// ---------------------------------------------------------------------------
extern "C" void kernel_launch(void* const* d_in, const int* in_sizes, int n_in,
                              void* d_out, int out_size, void* d_ws, size_t ws_size,
                              hipStream_t stream) {
    char* ws = (char*)d_ws;
    int* flag = (int*)ws;
    unsigned short* WT = (unsigned short*)(ws + 256);    // [4][1024][1024] bf16
    unsigned short* WqT = WT;
    unsigned short* WoT = WT + (size_t)3 * D_ * D_;
    float* biases = (float*)(WT + (size_t)4 * D_ * D_);  // [4][1024]
    float* bq = biases;
    float* bo = biases + 3 * 1024;
    unsigned short* Qp = (unsigned short*)(biases + 4 * 1024);  // [b][h][s][e]
    unsigned short* Kp = Qp + (size_t)BHSE_;                    // [b][h][s][e]
    unsigned short* Vp = Kp + (size_t)BHSE_;                    // [b][h][e][s]
    unsigned short* heads = Vp + (size_t)BHSE_;                 // [b*s][h*64+e]
    unsigned long long* packT = (unsigned long long*)(heads + (size_t)BHSE_);

    detect_dtype<<<1, 256, 0, stream>>>((const unsigned int*)d_in[0], flag);
    conv_w2<<<dim3(16, 16, 4), 256, 0, stream>>>(
        d_in[4], d_in[6], d_in[8], d_in[10],
        d_in[5], d_in[7], d_in[9], d_in[11], WT, biases, flag);
    maskpack<<<16384, 256, 0, stream>>>((const int*)d_in[3], packT);
    gemm_k<128, 0><<<768, 256, 0, stream>>>(
        d_in[0], d_in[1], d_in[2], WqT, bq, Qp, flag);
    attn64<<<1024, 256, 0, stream>>>(Qp, Kp, Vp, packT, heads);
    gemm_k<64, 1><<<512, 256, 0, stream>>>(
        heads, nullptr, nullptr, WoT, bo, d_out, flag);
}

// Round 6
// 309.027 us; speedup vs baseline: 1.2411x; 1.2411x over previous
//
#include <hip/hip_runtime.h>

// Problem constants (B,S,D,H,HD) = (4,1024,1024,16,64)
#define B_ 4
#define S_ 1024
#define D_ 1024
#define H_ 16
#define E_ 64
#define BS_ (B_*S_)
#define BHSE_ (B_*H_*S_*E_)   // 4,194,304

typedef __attribute__((ext_vector_type(8))) short bf16x8;   // 8 bf16 in 4 VGPRs
typedef __attribute__((ext_vector_type(4))) float f32x4;

__device__ __forceinline__ unsigned short f2bf(float f) {
    unsigned int x = __float_as_uint(f);
    x = (x + 0x7FFFu + ((x >> 16) & 1u)) >> 16;   // RNE
    return (unsigned short)x;
}
__device__ __forceinline__ float bf2f(unsigned short u) {
    return __uint_as_float(((unsigned int)u) << 16);
}
__device__ __forceinline__ float ldin(const void* p, size_t i, int isb) {
    return isb ? bf2f(((const unsigned short*)p)[i]) : ((const float*)p)[i];
}

// 2^x : v_exp_f32 is natively base-2
#if __has_builtin(__builtin_amdgcn_exp2f)
#define EXP2(x) __builtin_amdgcn_exp2f(x)
#else
#define EXP2(x) __expf((x) * 0.6931471805599453f)
#endif

// async global->LDS, 16B per lane; LDS dest = wave-uniform base + lane*16
__device__ __forceinline__ void gl2lds16(const void* g, void* l) {
    __builtin_amdgcn_global_load_lds(
        (const __attribute__((address_space(1))) void*)g,
        (__attribute__((address_space(3))) void*)l, 16, 0, 0);
}

// ---------------------------------------------------------------------------
// Kernel 0: detect input dtype (1=bf16, 0=fp32) -- see R0 notes.
// ---------------------------------------------------------------------------
__global__ void detect_dtype(const unsigned int* q, int* flag) {
    __shared__ int cnt;
    if (threadIdx.x == 0) cnt = 0;
    __syncthreads();
    unsigned int w = q[threadIdx.x];
    unsigned int lo = w & 0xFFFFu;
    unsigned int e = (lo >> 7) & 0xFFu;
    int ok = (lo == 0u) || (e >= 100u && e <= 145u);
    atomicAdd(&cnt, ok);
    __syncthreads();
    if (threadIdx.x == 0) flag[0] = (cnt >= 240) ? 1 : 0;
}

// ---------------------------------------------------------------------------
// Kernel 1: weight permutes via LDS-transposed 64x64 tiles (both directions
// coalesced). z=0..2: W{q,k,v}[h][d][e] -> WT[z][(h*64+e)][d];
// z=3: Wo[d][o] -> WT[3][o][d].
// ---------------------------------------------------------------------------
__global__ __launch_bounds__(256) void conv_w2(
        const void* Wq, const void* Wk, const void* Wv, const void* Wo,
        const void* bq_, const void* bk_, const void* bv_, const void* bo_,
        unsigned short* WT, float* biases, const int* flag) {
    __shared__ unsigned short Tt[64][72];
    const int isb = flag[0];
    const int z = blockIdx.z, t = threadIdx.x;
    const void* src = (z == 0) ? Wq : (z == 1) ? Wk : (z == 2) ? Wv : Wo;
    const int r0 = blockIdx.y * 64;          // d-tile origin
    const int c0 = blockIdx.x;               // head (z<3) or o-tile (z=3)
    {
        int dl = t >> 2, qc = t & 3;
        size_t base;
        if (z < 3) base = (size_t)c0 * 65536 + (size_t)(r0 + dl) * 64 + qc * 16;
        else       base = (size_t)(r0 + dl) * 1024 + (size_t)c0 * 64 + qc * 16;
        if (isb) {
            const unsigned short* s = (const unsigned short*)src + base;
            bf16x8 a0 = *(const bf16x8*)s, a1 = *(const bf16x8*)(s + 8);
#pragma unroll
            for (int j = 0; j < 8; j++) {
                Tt[qc * 16 + j][dl] = (unsigned short)a0[j];
                Tt[qc * 16 + 8 + j][dl] = (unsigned short)a1[j];
            }
        } else {
            const float* s = (const float*)src + base;
#pragma unroll
            for (int j = 0; j < 16; j++) Tt[qc * 16 + j][dl] = f2bf(s[j]);
        }
    }
    __syncthreads();
    {
        int el = t >> 2, qc = t & 3;
        size_t dst = (size_t)z * D_ * D_ + (size_t)(c0 * 64 + el) * D_ + r0 + qc * 16;
        *(bf16x8*)&WT[dst]     = *(const bf16x8*)&Tt[el][qc * 16];
        *(bf16x8*)&WT[dst + 8] = *(const bf16x8*)&Tt[el][qc * 16 + 8];
    }
    if (z == 3 && blockIdx.y == 0 && blockIdx.x < 4) {
        const void* bs = (blockIdx.x == 0) ? bq_ : (blockIdx.x == 1) ? bk_
                       : (blockIdx.x == 2) ? bv_ : bo_;
#pragma unroll
        for (int j = 0; j < 4; j++) {
            int i = t * 4 + j;
            biases[blockIdx.x * 1024 + i] = ldin(bs, i, isb);
        }
    }
}

// ---------------------------------------------------------------------------
// Kernel 2: mask bitpack, transposed: packT[b][kt][s] bit k = mask[b][s][kt*64+k]
// ---------------------------------------------------------------------------
__global__ void maskpack(const int* mask, unsigned long long* packT) {
    int W = blockIdx.x * 4 + (threadIdx.x >> 6);    // 0..65535
    int lane = threadIdx.x & 63;
    int b = W >> 14, rem = W & 16383, s = rem >> 4, kt = rem & 15;
    int mv = mask[((size_t)b * 1024 + s) * 1024 + kt * 64 + lane];
    unsigned long long bits = __ballot(mv != 0);
    if (lane == 0) packT[((size_t)b * 16 + kt) * 1024 + s] = bits;
}

// ---------------------------------------------------------------------------
// Kernel 3 (R6 = R4 structure + 2 deltas): bf16 MFMA GEMM, BK=32, 16KB LDS,
// global_load_lds staging, single-buffered 2-barrier K-loop (the measured-best
// R4 config). Deltas vs R4:
//  (1) XOR-4 LDS swizzle keyed on (row>>1)&3: slot s of row r holds global
//      granule s^((r>>1)&3) -> fragment reads are 2-way max = free (m136);
//      R5 measured the swizzle mechanism at 0 conflicts (was 3.1M).
//  (2) grid transposed (m fastest): the 8 n-blocks sharing one A m-tile land
//      on one XCD (linear%8 round-robin) -> A fetched once chip-wide.
// MODE 0: 3 projections (z: Q,K -> [b][h][s][e]; V -> [b][h][e][s]).
// MODE 1: final GEMM (A=heads bf16), writes d_out per dtype flag.
// ---------------------------------------------------------------------------
template<int BM, int MODE>
__global__ __launch_bounds__(256) void gemm_k(
        const void* A0, const void* A1, const void* A2,
        const unsigned short* BtB, const float* biasB, void* dstB, const int* flag) {
    constexpr int TOT16 = (BM + 128) * 32;      // LDS ushorts: [A BMx32 | B 128x32]
    constexpr int CALLS = TOT16 / 512;          // 1KB chunks (16 rows x 32 cols)
    constexpr int CPW = CALLS / 4;
    constexpr int MT = BM / 32;
    __shared__ unsigned short buf[TOT16];

    const int t = threadIdx.x, lane = t & 63, w = t >> 6;
    const int lm = lane & 15, q4 = lane >> 4;
    const int wm = w >> 1, wn = w & 1;
    const int lr = lane >> 2;                    // row-in-chunk 0..15
    const int ls = lane & 3;                     // LDS slot 0..3
    const int lg = ls ^ ((lr >> 1) & 3);         // source granule (swizzle)
    const int fl = flag[0];

    const void* A; const unsigned short* Bt; const float* bias;
    int aisb, z = 0;
    if (MODE == 0) {
        z = blockIdx.z;
        A = (z == 0) ? A0 : (z == 1 ? A1 : A2);
        Bt = BtB + (size_t)z * D_ * D_;
        bias = biasB + z * 1024;
        aisb = fl;
    } else {
        A = A0; Bt = BtB; bias = biasB; aisb = 1;
    }
    const int m0 = blockIdx.x * BM, n0 = blockIdx.y * 128;   // m fastest (XCD A-dedup)

    f32x4 acc[MT][4];
#pragma unroll
    for (int i = 0; i < MT; i++)
#pragma unroll
        for (int j = 0; j < 4; j++) acc[i][j] = (f32x4){0.f, 0.f, 0.f, 0.f};

    for (int kk = 0; kk < D_; kk += 32) {
        __syncthreads();                          // prior frag reads done
        // chunk c: rows c*16..c*16+15. Lane -> row c*16+lr, LDS slot ls,
        // global granule lg => LDS slot s of row r holds granule s^((r>>1)&3).
        if (aisb) {
#pragma unroll
            for (int i = 0; i < CPW; ++i) {
                int c = w * CPW + i;
                int row = c * 16 + lr;
                const unsigned short* g;
                if (row < BM)
                    g = (const unsigned short*)A + (size_t)(m0 + row) * D_ + kk + lg * 8;
                else
                    g = Bt + (size_t)(n0 + row - BM) * D_ + kk + lg * 8;
                gl2lds16(g, buf + c * 512);
            }
        } else {
            // fp32 A path: convert via regs into the same swizzled layout
#pragma unroll
            for (int i = 0; i < CPW; ++i) {
                int c = w * CPW + i;
                int row = c * 16 + lr;
                if (row < BM) {
                    const float* af = (const float*)A + (size_t)(m0 + row) * D_ + kk + lg * 8;
                    bf16x8 v;
#pragma unroll
                    for (int jj = 0; jj < 8; jj++) v[jj] = (short)f2bf(af[jj]);
                    *(bf16x8*)(buf + c * 512 + lane * 8) = v;
                } else {
                    gl2lds16(Bt + (size_t)(n0 + row - BM) * D_ + kk + lg * 8,
                             buf + c * 512);
                }
            }
        }
        __syncthreads();                          // drains vmcnt+lgkmcnt

        const unsigned short* As = buf;
        const unsigned short* Bs = buf + BM * 32;
        bf16x8 af[MT], bv[4];
#pragma unroll
        for (int mt = 0; mt < MT; mt++) {
            int row = wm * (BM / 2) + mt * 16 + lm;
            af[mt] = *(const bf16x8*)&As[row * 32 + (q4 ^ ((row >> 1) & 3)) * 8];
        }
#pragma unroll
        for (int nt = 0; nt < 4; nt++) {
            int row = wn * 64 + nt * 16 + lm;
            bv[nt] = *(const bf16x8*)&Bs[row * 32 + (q4 ^ ((row >> 1) & 3)) * 8];
        }
#pragma unroll
        for (int mt = 0; mt < MT; mt++)
#pragma unroll
            for (int nt = 0; nt < 4; nt++)
                acc[mt][nt] = __builtin_amdgcn_mfma_f32_16x16x32_bf16(
                    af[mt], bv[nt], acc[mt][nt], 0, 0, 0);
    }

    // epilogue: C/D layout col=lane&15, row=(lane>>4)*4+reg
#pragma unroll
    for (int mt = 0; mt < MT; mt++)
#pragma unroll
        for (int nt = 0; nt < 4; nt++)
#pragma unroll
            for (int r = 0; r < 4; r++) {
                int M = m0 + wm * (BM / 2) + mt * 16 + q4 * 4 + r;
                int N = n0 + wn * 64 + nt * 16 + lm;
                float v = acc[mt][nt][r] + bias[N];
                if (MODE == 0) {
                    int bb = M >> 10, s = M & 1023, hh = N >> 6, e = N & 63;
                    unsigned short* d16 = (unsigned short*)dstB + (size_t)z * BHSE_;
                    if (z < 2)
                        d16[((size_t)(bb * H_ + hh) * S_ + s) * E_ + e] = f2bf(v);
                    else
                        d16[((size_t)(bb * H_ + hh) * E_ + e) * S_ + s] = f2bf(v);
                } else {
                    size_t idx = (size_t)M * D_ + N;
                    if (fl) ((unsigned short*)dstB)[idx] = f2bf(v);
                    else    ((float*)dstB)[idx] = v;
                }
            }
}

// ---------------------------------------------------------------------------
// Kernel 4: fused attention — R4 config restored exactly (3-D grid, LDS
// double-buffered K/V DMA tiles, XOR swizzle, base-2 softmax, no barriers
// besides the staging one).
// ---------------------------------------------------------------------------
#define PSTR 88
__global__ __launch_bounds__(256) void attn64(
        const unsigned short* Qp, const unsigned short* Kp, const unsigned short* VpT,
        const unsigned long long* packT, unsigned short* heads) {
    __shared__ unsigned short KT[2][4096];   // [buf][64 keys x 64 e], swizzled
    __shared__ unsigned short VT[2][4096];   // [buf][64 e x 64 keys], swizzled
    __shared__ unsigned short Pw[4][16 * PSTR];

    const int qt = blockIdx.x, h = blockIdx.y, b = blockIdx.z;
    const int t = threadIdx.x, w = t >> 6, lane = t & 63, lm = lane & 15, q4 = lane >> 4;
    const size_t bh = ((size_t)b * H_ + h) * S_ * E_;
    const unsigned short* Qb = Qp + bh;
    const unsigned short* Kb = Kp + bh;
    const unsigned short* Vb = VpT + bh;                // Vb[e*1024 + s]
    const int q0 = qt * 64 + w * 16;
    unsigned short* P = &Pw[w][0];

    // per-lane invariant DMA source offsets (ushort units)
    const int l3 = lane >> 3, l7 = lane & 7;
    const int kLaneOff = l3 * 64 + (l7 ^ l3) * 8;       // within an 8-row K chunk
    const int vLaneOff = l3 * 1024 + (l7 ^ l3) * 8;     // within an 8-row V chunk

    // swizzled LDS fragment chunk indices (granule = 8 ushorts)
    const int sw = lm & 7;
    const int c0 = (q4 ^ sw) * 8, c1 = ((q4 ^ 4) ^ sw) * 8;

    // Q B-fragments, held for the whole sweep
    bf16x8 bq0 = *(const bf16x8*)&Qb[(size_t)(q0 + lm) * E_ + q4 * 8];
    bf16x8 bq1 = *(const bf16x8*)&Qb[(size_t)(q0 + lm) * E_ + 32 + q4 * 8];

    f32x4 oacc[4];
#pragma unroll
    for (int i = 0; i < 4; i++) oacc[i] = (f32x4){0.f, 0.f, 0.f, 0.f};
    float mrun = -3.0e38f, lrun = 0.f;
    const float scale2 = 0.03125f * 1.4426950408889634f;   // log2e / sqrt(D)

#define STAGE(ktile, bufi)                                                    \
    {                                                                         \
        int k0s = (ktile) * 64;                                               \
        _Pragma("unroll")                                                     \
        for (int i_ = 0; i_ < 4; ++i_) {                                      \
            int c_ = w * 4 + i_;                                              \
            if (c_ < 8) {                                                     \
                gl2lds16(Kb + (size_t)k0s * 64 + c_ * 512 + kLaneOff,         \
                         &KT[bufi][c_ * 512]);                                \
            } else {                                                          \
                int cc_ = c_ - 8;                                             \
                gl2lds16(Vb + (size_t)cc_ * 8192 + k0s + vLaneOff,            \
                         &VT[bufi][cc_ * 512]);                               \
            }                                                                 \
        }                                                                     \
    }

    STAGE(0, 0)

    for (int kt = 0; kt < S_ / 64; ++kt) {
        const int bufi = kt & 1;
        __syncthreads();                 // own-vmcnt drain + barrier: tile kt ready
        if (kt < 15) STAGE(kt + 1, bufi ^ 1)

        unsigned long long mk = packT[((size_t)b * 16 + kt) * 1024 + q0 + lm];

        // Sc^T from LDS K tile
        f32x4 st[4];
#pragma unroll
        for (int jt = 0; jt < 4; ++jt) {
            const unsigned short* kr = &KT[bufi][(jt * 16 + lm) * 64];
            bf16x8 ka0 = *(const bf16x8*)&kr[c0];
            bf16x8 ka1 = *(const bf16x8*)&kr[c1];
            f32x4 zz = (f32x4){0.f, 0.f, 0.f, 0.f};
            zz = __builtin_amdgcn_mfma_f32_16x16x32_bf16(ka0, bq0, zz, 0, 0, 0);
            zz = __builtin_amdgcn_mfma_f32_16x16x32_bf16(ka1, bq1, zz, 0, 0, 0);
            st[jt] = zz;
        }
        float sv[4][4];
        float tmx = -3.0e38f;
#pragma unroll
        for (int jt = 0; jt < 4; ++jt)
#pragma unroll
            for (int r = 0; r < 4; r++) {
                int kb = jt * 16 + q4 * 4 + r;
                float xm = ((mk >> kb) & 1ull) ? st[jt][r] * scale2 : -3.0e38f;
                sv[jt][r] = xm;
                tmx = fmaxf(tmx, xm);
            }
        tmx = fmaxf(tmx, __shfl_xor(tmx, 16, 64));
        tmx = fmaxf(tmx, __shfl_xor(tmx, 32, 64));
        float mnew = fmaxf(mrun, tmx);
        float alpha = EXP2(mrun - mnew);
        float ssum = 0.f;
        unsigned long long pk[4];
#pragma unroll
        for (int jt = 0; jt < 4; ++jt) {
            float p0 = EXP2(sv[jt][0] - mnew);
            float p1 = EXP2(sv[jt][1] - mnew);
            float p2 = EXP2(sv[jt][2] - mnew);
            float p3 = EXP2(sv[jt][3] - mnew);
            ssum += (p0 + p1) + (p2 + p3);
            pk[jt] = (unsigned long long)f2bf(p0)
                   | ((unsigned long long)f2bf(p1) << 16)
                   | ((unsigned long long)f2bf(p2) << 32)
                   | ((unsigned long long)f2bf(p3) << 48);
        }
        ssum += __shfl_xor(ssum, 16, 64);
        ssum += __shfl_xor(ssum, 32, 64);
        lrun = lrun * alpha + ssum;
        mrun = mnew;
#pragma unroll
        for (int nt = 0; nt < 4; nt++) oacc[nt] = oacc[nt] * alpha;

        // P C->B layout via per-wave LDS (in-order DS pipe, no barrier)
#pragma unroll
        for (int jt = 0; jt < 4; ++jt)
            *(unsigned long long*)&P[lm * PSTR + jt * 16 + q4 * 4] = pk[jt];
        bf16x8 bp0 = *(const bf16x8*)&P[lm * PSTR + q4 * 8];
        bf16x8 bp1 = *(const bf16x8*)&P[lm * PSTR + 32 + q4 * 8];

        // PV from LDS V tile
#pragma unroll
        for (int nt = 0; nt < 4; nt++) {
            const unsigned short* vr = &VT[bufi][(nt * 16 + lm) * 64];
            bf16x8 va0 = *(const bf16x8*)&vr[c0];
            bf16x8 va1 = *(const bf16x8*)&vr[c1];
            oacc[nt] = __builtin_amdgcn_mfma_f32_16x16x32_bf16(va0, bp0, oacc[nt], 0, 0, 0);
            oacc[nt] = __builtin_amdgcn_mfma_f32_16x16x32_bf16(va1, bp1, oacc[nt], 0, 0, 0);
        }
    }

    float inv = 1.0f / lrun;
#pragma unroll
    for (int nt = 0; nt < 4; nt++) {
        unsigned long long hv =
              (unsigned long long)f2bf(oacc[nt][0] * inv)
            | ((unsigned long long)f2bf(oacc[nt][1] * inv) << 16)
            | ((unsigned long long)f2bf(oacc[nt][2] * inv) << 32)
            | ((unsigned long long)f2bf(oacc[nt][3] * inv) << 48);
        *(unsigned long long*)&heads[(size_t)(b * S_ + q0 + lm) * D_ + h * E_ + nt * 16 + q4 * 4] = hv;
    }
}

// ---------------------------------------------------------------------------
extern "C" void kernel_launch(void* const* d_in, const int* in_sizes, int n_in,
                              void* d_out, int out_size, void* d_ws, size_t ws_size,
                              hipStream_t stream) {
    char* ws = (char*)d_ws;
    int* flag = (int*)ws;
    unsigned short* WT = (unsigned short*)(ws + 256);    // [4][1024][1024] bf16
    unsigned short* WqT = WT;
    unsigned short* WoT = WT + (size_t)3 * D_ * D_;
    float* biases = (float*)(WT + (size_t)4 * D_ * D_);  // [4][1024]
    float* bq = biases;
    float* bo = biases + 3 * 1024;
    unsigned short* Qp = (unsigned short*)(biases + 4 * 1024);  // [b][h][s][e]
    unsigned short* Kp = Qp + (size_t)BHSE_;                    // [b][h][s][e]
    unsigned short* Vp = Kp + (size_t)BHSE_;                    // [b][h][e][s]
    unsigned short* heads = Vp + (size_t)BHSE_;                 // [b*s][h*64+e]
    unsigned long long* packT = (unsigned long long*)(heads + (size_t)BHSE_);

    detect_dtype<<<1, 256, 0, stream>>>((const unsigned int*)d_in[0], flag);
    conv_w2<<<dim3(16, 16, 4), 256, 0, stream>>>(
        d_in[4], d_in[6], d_in[8], d_in[10],
        d_in[5], d_in[7], d_in[9], d_in[11], WT, biases, flag);
    maskpack<<<16384, 256, 0, stream>>>((const int*)d_in[3], packT);
    gemm_k<128, 0><<<dim3(32, 8, 3), 256, 0, stream>>>(
        d_in[0], d_in[1], d_in[2], WqT, bq, Qp, flag);
    attn64<<<dim3(16, 16, 4), 256, 0, stream>>>(Qp, Kp, Vp, packT, heads);
    gemm_k<64, 1><<<dim3(64, 8, 1), 256, 0, stream>>>(
        heads, nullptr, nullptr, WoT, bo, d_out, flag);
}

// Round 7
// 302.146 us; speedup vs baseline: 1.2694x; 1.0228x over previous
//
#include <hip/hip_runtime.h>

// Problem constants (B,S,D,H,HD) = (4,1024,1024,16,64)
#define B_ 4
#define S_ 1024
#define D_ 1024
#define H_ 16
#define E_ 64
#define BS_ (B_*S_)
#define BHSE_ (B_*H_*S_*E_)   // 4,194,304

typedef __attribute__((ext_vector_type(8))) short bf16x8;   // 8 bf16 in 4 VGPRs
typedef __attribute__((ext_vector_type(4))) float f32x4;

__device__ __forceinline__ unsigned short f2bf(float f) {
    unsigned int x = __float_as_uint(f);
    x = (x + 0x7FFFu + ((x >> 16) & 1u)) >> 16;   // RNE
    return (unsigned short)x;
}
__device__ __forceinline__ float bf2f(unsigned short u) {
    return __uint_as_float(((unsigned int)u) << 16);
}
__device__ __forceinline__ float ldin(const void* p, size_t i, int isb) {
    return isb ? bf2f(((const unsigned short*)p)[i]) : ((const float*)p)[i];
}

// 2^x : v_exp_f32 is natively base-2
#if __has_builtin(__builtin_amdgcn_exp2f)
#define EXP2(x) __builtin_amdgcn_exp2f(x)
#else
#define EXP2(x) __expf((x) * 0.6931471805599453f)
#endif

// async global->LDS, 16B per lane; LDS dest = wave-uniform base + lane*16
__device__ __forceinline__ void gl2lds16(const void* g, void* l) {
    __builtin_amdgcn_global_load_lds(
        (const __attribute__((address_space(1))) void*)g,
        (__attribute__((address_space(3))) void*)l, 16, 0, 0);
}

// ---------------------------------------------------------------------------
// Kernel 0: detect input dtype (1=bf16, 0=fp32) -- see R0 notes.
// ---------------------------------------------------------------------------
__global__ void detect_dtype(const unsigned int* q, int* flag) {
    __shared__ int cnt;
    if (threadIdx.x == 0) cnt = 0;
    __syncthreads();
    unsigned int w = q[threadIdx.x];
    unsigned int lo = w & 0xFFFFu;
    unsigned int e = (lo >> 7) & 0xFFu;
    int ok = (lo == 0u) || (e >= 100u && e <= 145u);
    atomicAdd(&cnt, ok);
    __syncthreads();
    if (threadIdx.x == 0) flag[0] = (cnt >= 240) ? 1 : 0;
}

// ---------------------------------------------------------------------------
// Kernel 1: weight permutes via LDS-transposed 64x64 tiles (both directions
// coalesced). z=0..2: W{q,k,v}[h][d][e] -> WT[z][(h*64+e)][d];
// z=3: Wo[d][o] -> WT[3][o][d].
// ---------------------------------------------------------------------------
__global__ __launch_bounds__(256) void conv_w2(
        const void* Wq, const void* Wk, const void* Wv, const void* Wo,
        const void* bq_, const void* bk_, const void* bv_, const void* bo_,
        unsigned short* WT, float* biases, const int* flag) {
    __shared__ unsigned short Tt[64][72];
    const int isb = flag[0];
    const int z = blockIdx.z, t = threadIdx.x;
    const void* src = (z == 0) ? Wq : (z == 1) ? Wk : (z == 2) ? Wv : Wo;
    const int r0 = blockIdx.y * 64;          // d-tile origin
    const int c0 = blockIdx.x;               // head (z<3) or o-tile (z=3)
    {
        int dl = t >> 2, qc = t & 3;
        size_t base;
        if (z < 3) base = (size_t)c0 * 65536 + (size_t)(r0 + dl) * 64 + qc * 16;
        else       base = (size_t)(r0 + dl) * 1024 + (size_t)c0 * 64 + qc * 16;
        if (isb) {
            const unsigned short* s = (const unsigned short*)src + base;
            bf16x8 a0 = *(const bf16x8*)s, a1 = *(const bf16x8*)(s + 8);
#pragma unroll
            for (int j = 0; j < 8; j++) {
                Tt[qc * 16 + j][dl] = (unsigned short)a0[j];
                Tt[qc * 16 + 8 + j][dl] = (unsigned short)a1[j];
            }
        } else {
            const float* s = (const float*)src + base;
#pragma unroll
            for (int j = 0; j < 16; j++) Tt[qc * 16 + j][dl] = f2bf(s[j]);
        }
    }
    __syncthreads();
    {
        int el = t >> 2, qc = t & 3;
        size_t dst = (size_t)z * D_ * D_ + (size_t)(c0 * 64 + el) * D_ + r0 + qc * 16;
        *(bf16x8*)&WT[dst]     = *(const bf16x8*)&Tt[el][qc * 16];
        *(bf16x8*)&WT[dst + 8] = *(const bf16x8*)&Tt[el][qc * 16 + 8];
    }
    if (z == 3 && blockIdx.y == 0 && blockIdx.x < 4) {
        const void* bs = (blockIdx.x == 0) ? bq_ : (blockIdx.x == 1) ? bk_
                       : (blockIdx.x == 2) ? bv_ : bo_;
#pragma unroll
        for (int j = 0; j < 4; j++) {
            int i = t * 4 + j;
            biases[blockIdx.x * 1024 + i] = ldin(bs, i, isb);
        }
    }
}

// ---------------------------------------------------------------------------
// Kernel 2: mask bitpack, transposed: packT[b][kt][s] bit k = mask[b][s][kt*64+k]
// ---------------------------------------------------------------------------
__global__ void maskpack(const int* mask, unsigned long long* packT) {
    int W = blockIdx.x * 4 + (threadIdx.x >> 6);    // 0..65535
    int lane = threadIdx.x & 63;
    int b = W >> 14, rem = W & 16383, s = rem >> 4, kt = rem & 15;
    int mv = mask[((size_t)b * 1024 + s) * 1024 + kt * 64 + lane];
    unsigned long long bits = __ballot(mv != 0);
    if (lane == 0) packT[((size_t)b * 16 + kt) * 1024 + s] = bits;
}

// ---------------------------------------------------------------------------
// Kernel 3 (R7): bf16 MFMA GEMM, BK=32, XOR-4 swizzle (0 conflicts, R6-
// verified), m-fastest grid (A dedup, R6-verified), and NEW: attn64-style
// DMA double-buffer — ONE barrier per K-iter; the vmcnt(0) drain at the
// barrier covers a prefetch issued a full compute-phase earlier, so load
// latency is absorbed in-iteration instead of stalling all (convoyed) waves.
// MODE 0: 3 projections (z: Q,K -> [b][h][s][e]; V -> [b][h][e][s]).
// MODE 1: final GEMM (A=heads bf16), writes d_out per dtype flag.
// ---------------------------------------------------------------------------
template<int BM, int MODE>
__global__ __launch_bounds__(256) void gemm_k(
        const void* A0, const void* A1, const void* A2,
        const unsigned short* BtB, const float* biasB, void* dstB, const int* flag) {
    constexpr int TOT16 = (BM + 128) * 32;      // ushorts per buffer
    constexpr int CALLS = TOT16 / 512;          // 1KB chunks (16 rows x 32 cols)
    constexpr int CPW = CALLS / 4;
    constexpr int MT = BM / 32;
    __shared__ unsigned short buf[2][TOT16];

    const int t = threadIdx.x, lane = t & 63, w = t >> 6;
    const int lm = lane & 15, q4 = lane >> 4;
    const int wm = w >> 1, wn = w & 1;
    const int lr = lane >> 2;                    // row-in-chunk 0..15
    const int ls = lane & 3;                     // LDS slot 0..3
    const int lg = ls ^ ((lr >> 1) & 3);         // source granule (swizzle)
    const int fl = flag[0];

    const void* A; const unsigned short* Bt; const float* bias;
    int aisb, z = 0;
    if (MODE == 0) {
        z = blockIdx.z;
        A = (z == 0) ? A0 : (z == 1 ? A1 : A2);
        Bt = BtB + (size_t)z * D_ * D_;
        bias = biasB + z * 1024;
        aisb = fl;
    } else {
        A = A0; Bt = BtB; bias = biasB; aisb = 1;
    }
    const int m0 = blockIdx.x * BM, n0 = blockIdx.y * 128;   // m fastest (XCD A-dedup)

    // stage K-slice kk into buffer bi (swizzled: slot s of row r holds
    // global granule s ^ ((r>>1)&3))
    auto stage = [&](int kk, int bi) {
        if (aisb) {
#pragma unroll
            for (int i = 0; i < CPW; ++i) {
                int c = w * CPW + i;
                int row = c * 16 + lr;
                const unsigned short* g;
                if (row < BM)
                    g = (const unsigned short*)A + (size_t)(m0 + row) * D_ + kk + lg * 8;
                else
                    g = Bt + (size_t)(n0 + row - BM) * D_ + kk + lg * 8;
                gl2lds16(g, &buf[bi][c * 512]);
            }
        } else {
            // fp32 A path: convert via regs into the same swizzled layout
#pragma unroll
            for (int i = 0; i < CPW; ++i) {
                int c = w * CPW + i;
                int row = c * 16 + lr;
                if (row < BM) {
                    const float* af = (const float*)A + (size_t)(m0 + row) * D_ + kk + lg * 8;
                    bf16x8 v;
#pragma unroll
                    for (int jj = 0; jj < 8; jj++) v[jj] = (short)f2bf(af[jj]);
                    *(bf16x8*)(&buf[bi][c * 512 + lane * 8]) = v;
                } else {
                    gl2lds16(Bt + (size_t)(n0 + row - BM) * D_ + kk + lg * 8,
                             &buf[bi][c * 512]);
                }
            }
        }
    };

    f32x4 acc[MT][4];
#pragma unroll
    for (int i = 0; i < MT; i++)
#pragma unroll
        for (int j = 0; j < 4; j++) acc[i][j] = (f32x4){0.f, 0.f, 0.f, 0.f};

    stage(0, 0);
    for (int it = 0; it < D_ / 32; ++it) {
        const int bi = it & 1;
        __syncthreads();                 // drains the prefetch of slice `it`
        if (it < D_ / 32 - 1) stage((it + 1) * 32, bi ^ 1);

        const unsigned short* As = buf[bi];
        const unsigned short* Bs = buf[bi] + BM * 32;
        bf16x8 af[MT], bv[4];
#pragma unroll
        for (int mt = 0; mt < MT; mt++) {
            int row = wm * (BM / 2) + mt * 16 + lm;
            af[mt] = *(const bf16x8*)&As[row * 32 + (q4 ^ ((row >> 1) & 3)) * 8];
        }
#pragma unroll
        for (int nt = 0; nt < 4; nt++) {
            int row = wn * 64 + nt * 16 + lm;
            bv[nt] = *(const bf16x8*)&Bs[row * 32 + (q4 ^ ((row >> 1) & 3)) * 8];
        }
#pragma unroll
        for (int mt = 0; mt < MT; mt++)
#pragma unroll
            for (int nt = 0; nt < 4; nt++)
                acc[mt][nt] = __builtin_amdgcn_mfma_f32_16x16x32_bf16(
                    af[mt], bv[nt], acc[mt][nt], 0, 0, 0);
    }

    // epilogue: C/D layout col=lane&15, row=(lane>>4)*4+reg
#pragma unroll
    for (int mt = 0; mt < MT; mt++)
#pragma unroll
        for (int nt = 0; nt < 4; nt++) {
            int N = n0 + wn * 64 + nt * 16 + lm;
            int Mb = m0 + wm * (BM / 2) + mt * 16 + q4 * 4;
            if (MODE == 0 && z == 2) {
                // V^T: 4 consecutive s per lane -> one b64 store (4x fewer,
                // 4x larger segments than per-element scatter)
                int bb = Mb >> 10, sb = Mb & 1023, hh = N >> 6, e = N & 63;
                unsigned long long hv = 0;
#pragma unroll
                for (int r = 0; r < 4; r++)
                    hv |= (unsigned long long)f2bf(acc[mt][nt][r] + bias[N]) << (16 * r);
                unsigned short* d16 = (unsigned short*)dstB + (size_t)2 * BHSE_;
                *(unsigned long long*)&d16[(((size_t)(bb * H_ + hh) * E_ + e) << 10) + sb] = hv;
            } else {
#pragma unroll
                for (int r = 0; r < 4; r++) {
                    int M = Mb + r;
                    float v = acc[mt][nt][r] + bias[N];
                    if (MODE == 0) {
                        int bb = M >> 10, s = M & 1023, hh = N >> 6, e = N & 63;
                        unsigned short* d16 = (unsigned short*)dstB + (size_t)z * BHSE_;
                        d16[((size_t)(bb * H_ + hh) * S_ + s) * E_ + e] = f2bf(v);
                    } else {
                        size_t idx = (size_t)M * D_ + N;
                        if (fl) ((unsigned short*)dstB)[idx] = f2bf(v);
                        else    ((float*)dstB)[idx] = v;
                    }
                }
            }
        }
}

// ---------------------------------------------------------------------------
// Kernel 4: fused attention — R4 config (3-D grid, LDS double-buffered K/V
// DMA tiles, XOR swizzle, base-2 softmax). Unchanged from R6.
// ---------------------------------------------------------------------------
#define PSTR 88
__global__ __launch_bounds__(256) void attn64(
        const unsigned short* Qp, const unsigned short* Kp, const unsigned short* VpT,
        const unsigned long long* packT, unsigned short* heads) {
    __shared__ unsigned short KT[2][4096];   // [buf][64 keys x 64 e], swizzled
    __shared__ unsigned short VT[2][4096];   // [buf][64 e x 64 keys], swizzled
    __shared__ unsigned short Pw[4][16 * PSTR];

    const int qt = blockIdx.x, h = blockIdx.y, b = blockIdx.z;
    const int t = threadIdx.x, w = t >> 6, lane = t & 63, lm = lane & 15, q4 = lane >> 4;
    const size_t bh = ((size_t)b * H_ + h) * S_ * E_;
    const unsigned short* Qb = Qp + bh;
    const unsigned short* Kb = Kp + bh;
    const unsigned short* Vb = VpT + bh;                // Vb[e*1024 + s]
    const int q0 = qt * 64 + w * 16;
    unsigned short* P = &Pw[w][0];

    // per-lane invariant DMA source offsets (ushort units)
    const int l3 = lane >> 3, l7 = lane & 7;
    const int kLaneOff = l3 * 64 + (l7 ^ l3) * 8;       // within an 8-row K chunk
    const int vLaneOff = l3 * 1024 + (l7 ^ l3) * 8;     // within an 8-row V chunk

    // swizzled LDS fragment chunk indices (granule = 8 ushorts)
    const int sw = lm & 7;
    const int c0 = (q4 ^ sw) * 8, c1 = ((q4 ^ 4) ^ sw) * 8;

    // Q B-fragments, held for the whole sweep
    bf16x8 bq0 = *(const bf16x8*)&Qb[(size_t)(q0 + lm) * E_ + q4 * 8];
    bf16x8 bq1 = *(const bf16x8*)&Qb[(size_t)(q0 + lm) * E_ + 32 + q4 * 8];

    f32x4 oacc[4];
#pragma unroll
    for (int i = 0; i < 4; i++) oacc[i] = (f32x4){0.f, 0.f, 0.f, 0.f};
    float mrun = -3.0e38f, lrun = 0.f;
    const float scale2 = 0.03125f * 1.4426950408889634f;   // log2e / sqrt(D)

#define STAGE(ktile, bufi)                                                    \
    {                                                                         \
        int k0s = (ktile) * 64;                                               \
        _Pragma("unroll")                                                     \
        for (int i_ = 0; i_ < 4; ++i_) {                                      \
            int c_ = w * 4 + i_;                                              \
            if (c_ < 8) {                                                     \
                gl2lds16(Kb + (size_t)k0s * 64 + c_ * 512 + kLaneOff,         \
                         &KT[bufi][c_ * 512]);                                \
            } else {                                                          \
                int cc_ = c_ - 8;                                             \
                gl2lds16(Vb + (size_t)cc_ * 8192 + k0s + vLaneOff,            \
                         &VT[bufi][cc_ * 512]);                               \
            }                                                                 \
        }                                                                     \
    }

    STAGE(0, 0)

    for (int kt = 0; kt < S_ / 64; ++kt) {
        const int bufi = kt & 1;
        __syncthreads();                 // own-vmcnt drain + barrier: tile kt ready
        if (kt < 15) STAGE(kt + 1, bufi ^ 1)

        unsigned long long mk = packT[((size_t)b * 16 + kt) * 1024 + q0 + lm];

        // Sc^T from LDS K tile
        f32x4 st[4];
#pragma unroll
        for (int jt = 0; jt < 4; ++jt) {
            const unsigned short* kr = &KT[bufi][(jt * 16 + lm) * 64];
            bf16x8 ka0 = *(const bf16x8*)&kr[c0];
            bf16x8 ka1 = *(const bf16x8*)&kr[c1];
            f32x4 zz = (f32x4){0.f, 0.f, 0.f, 0.f};
            zz = __builtin_amdgcn_mfma_f32_16x16x32_bf16(ka0, bq0, zz, 0, 0, 0);
            zz = __builtin_amdgcn_mfma_f32_16x16x32_bf16(ka1, bq1, zz, 0, 0, 0);
            st[jt] = zz;
        }
        float sv[4][4];
        float tmx = -3.0e38f;
#pragma unroll
        for (int jt = 0; jt < 4; ++jt)
#pragma unroll
            for (int r = 0; r < 4; r++) {
                int kb = jt * 16 + q4 * 4 + r;
                float xm = ((mk >> kb) & 1ull) ? st[jt][r] * scale2 : -3.0e38f;
                sv[jt][r] = xm;
                tmx = fmaxf(tmx, xm);
            }
        tmx = fmaxf(tmx, __shfl_xor(tmx, 16, 64));
        tmx = fmaxf(tmx, __shfl_xor(tmx, 32, 64));
        float mnew = fmaxf(mrun, tmx);
        float alpha = EXP2(mrun - mnew);
        float ssum = 0.f;
        unsigned long long pk[4];
#pragma unroll
        for (int jt = 0; jt < 4; ++jt) {
            float p0 = EXP2(sv[jt][0] - mnew);
            float p1 = EXP2(sv[jt][1] - mnew);
            float p2 = EXP2(sv[jt][2] - mnew);
            float p3 = EXP2(sv[jt][3] - mnew);
            ssum += (p0 + p1) + (p2 + p3);
            pk[jt] = (unsigned long long)f2bf(p0)
                   | ((unsigned long long)f2bf(p1) << 16)
                   | ((unsigned long long)f2bf(p2) << 32)
                   | ((unsigned long long)f2bf(p3) << 48);
        }
        ssum += __shfl_xor(ssum, 16, 64);
        ssum += __shfl_xor(ssum, 32, 64);
        lrun = lrun * alpha + ssum;
        mrun = mnew;
#pragma unroll
        for (int nt = 0; nt < 4; nt++) oacc[nt] = oacc[nt] * alpha;

        // P C->B layout via per-wave LDS (in-order DS pipe, no barrier)
#pragma unroll
        for (int jt = 0; jt < 4; ++jt)
            *(unsigned long long*)&P[lm * PSTR + jt * 16 + q4 * 4] = pk[jt];
        bf16x8 bp0 = *(const bf16x8*)&P[lm * PSTR + q4 * 8];
        bf16x8 bp1 = *(const bf16x8*)&P[lm * PSTR + 32 + q4 * 8];

        // PV from LDS V tile
#pragma unroll
        for (int nt = 0; nt < 4; nt++) {
            const unsigned short* vr = &VT[bufi][(nt * 16 + lm) * 64];
            bf16x8 va0 = *(const bf16x8*)&vr[c0];
            bf16x8 va1 = *(const bf16x8*)&vr[c1];
            oacc[nt] = __builtin_amdgcn_mfma_f32_16x16x32_bf16(va0, bp0, oacc[nt], 0, 0, 0);
            oacc[nt] = __builtin_amdgcn_mfma_f32_16x16x32_bf16(va1, bp1, oacc[nt], 0, 0, 0);
        }
    }

    float inv = 1.0f / lrun;
#pragma unroll
    for (int nt = 0; nt < 4; nt++) {
        unsigned long long hv =
              (unsigned long long)f2bf(oacc[nt][0] * inv)
            | ((unsigned long long)f2bf(oacc[nt][1] * inv) << 16)
            | ((unsigned long long)f2bf(oacc[nt][2] * inv) << 32)
            | ((unsigned long long)f2bf(oacc[nt][3] * inv) << 48);
        *(unsigned long long*)&heads[(size_t)(b * S_ + q0 + lm) * D_ + h * E_ + nt * 16 + q4 * 4] = hv;
    }
}

// ---------------------------------------------------------------------------
extern "C" void kernel_launch(void* const* d_in, const int* in_sizes, int n_in,
                              void* d_out, int out_size, void* d_ws, size_t ws_size,
                              hipStream_t stream) {
    char* ws = (char*)d_ws;
    int* flag = (int*)ws;
    unsigned short* WT = (unsigned short*)(ws + 256);    // [4][1024][1024] bf16
    unsigned short* WqT = WT;
    unsigned short* WoT = WT + (size_t)3 * D_ * D_;
    float* biases = (float*)(WT + (size_t)4 * D_ * D_);  // [4][1024]
    float* bq = biases;
    float* bo = biases + 3 * 1024;
    unsigned short* Qp = (unsigned short*)(biases + 4 * 1024);  // [b][h][s][e]
    unsigned short* Kp = Qp + (size_t)BHSE_;                    // [b][h][s][e]
    unsigned short* Vp = Kp + (size_t)BHSE_;                    // [b][h][e][s]
    unsigned short* heads = Vp + (size_t)BHSE_;                 // [b*s][h*64+e]
    unsigned long long* packT = (unsigned long long*)(heads + (size_t)BHSE_);

    detect_dtype<<<1, 256, 0, stream>>>((const unsigned int*)d_in[0], flag);
    conv_w2<<<dim3(16, 16, 4), 256, 0, stream>>>(
        d_in[4], d_in[6], d_in[8], d_in[10],
        d_in[5], d_in[7], d_in[9], d_in[11], WT, biases, flag);
    maskpack<<<16384, 256, 0, stream>>>((const int*)d_in[3], packT);
    gemm_k<128, 0><<<dim3(32, 8, 3), 256, 0, stream>>>(
        d_in[0], d_in[1], d_in[2], WqT, bq, Qp, flag);
    attn64<<<dim3(16, 16, 4), 256, 0, stream>>>(Qp, Kp, Vp, packT, heads);
    gemm_k<64, 1><<<dim3(64, 8, 1), 256, 0, stream>>>(
        heads, nullptr, nullptr, WoT, bo, d_out, flag);
}

// Round 8
// 292.870 us; speedup vs baseline: 1.3096x; 1.0317x over previous
//
#include <hip/hip_runtime.h>

// Problem constants (B,S,D,H,HD) = (4,1024,1024,16,64)
#define B_ 4
#define S_ 1024
#define D_ 1024
#define H_ 16
#define E_ 64
#define BS_ (B_*S_)
#define BHSE_ (B_*H_*S_*E_)   // 4,194,304

typedef __attribute__((ext_vector_type(8))) short bf16x8;   // 8 bf16 in 4 VGPRs
typedef __attribute__((ext_vector_type(4))) float f32x4;

__device__ __forceinline__ unsigned short f2bf(float f) {
    unsigned int x = __float_as_uint(f);
    x = (x + 0x7FFFu + ((x >> 16) & 1u)) >> 16;   // RNE
    return (unsigned short)x;
}
__device__ __forceinline__ float bf2f(unsigned short u) {
    return __uint_as_float(((unsigned int)u) << 16);
}
__device__ __forceinline__ float ldin(const void* p, size_t i, int isb) {
    return isb ? bf2f(((const unsigned short*)p)[i]) : ((const float*)p)[i];
}

// 2^x : v_exp_f32 is natively base-2
#if __has_builtin(__builtin_amdgcn_exp2f)
#define EXP2(x) __builtin_amdgcn_exp2f(x)
#else
#define EXP2(x) __expf((x) * 0.6931471805599453f)
#endif

// async global->LDS, 16B per lane; LDS dest = wave-uniform base + lane*16
__device__ __forceinline__ void gl2lds16(const void* g, void* l) {
    __builtin_amdgcn_global_load_lds(
        (const __attribute__((address_space(1))) void*)g,
        (__attribute__((address_space(3))) void*)l, 16, 0, 0);
}

// ---------------------------------------------------------------------------
// Kernel 0: detect input dtype (1=bf16, 0=fp32) -- see R0 notes.
// ---------------------------------------------------------------------------
__global__ void detect_dtype(const unsigned int* q, int* flag) {
    __shared__ int cnt;
    if (threadIdx.x == 0) cnt = 0;
    __syncthreads();
    unsigned int w = q[threadIdx.x];
    unsigned int lo = w & 0xFFFFu;
    unsigned int e = (lo >> 7) & 0xFFu;
    int ok = (lo == 0u) || (e >= 100u && e <= 145u);
    atomicAdd(&cnt, ok);
    __syncthreads();
    if (threadIdx.x == 0) flag[0] = (cnt >= 240) ? 1 : 0;
}

// ---------------------------------------------------------------------------
// Kernel 1: weight permutes via LDS-transposed 64x64 tiles (both directions
// coalesced). z=0..2: W{q,k,v}[h][d][e] -> WT[z][(h*64+e)][d];
// z=3: Wo[d][o] -> WT[3][o][d].
// ---------------------------------------------------------------------------
__global__ __launch_bounds__(256) void conv_w2(
        const void* Wq, const void* Wk, const void* Wv, const void* Wo,
        const void* bq_, const void* bk_, const void* bv_, const void* bo_,
        unsigned short* WT, float* biases, const int* flag) {
    __shared__ unsigned short Tt[64][72];
    const int isb = flag[0];
    const int z = blockIdx.z, t = threadIdx.x;
    const void* src = (z == 0) ? Wq : (z == 1) ? Wk : (z == 2) ? Wv : Wo;
    const int r0 = blockIdx.y * 64;          // d-tile origin
    const int c0 = blockIdx.x;               // head (z<3) or o-tile (z=3)
    {
        int dl = t >> 2, qc = t & 3;
        size_t base;
        if (z < 3) base = (size_t)c0 * 65536 + (size_t)(r0 + dl) * 64 + qc * 16;
        else       base = (size_t)(r0 + dl) * 1024 + (size_t)c0 * 64 + qc * 16;
        if (isb) {
            const unsigned short* s = (const unsigned short*)src + base;
            bf16x8 a0 = *(const bf16x8*)s, a1 = *(const bf16x8*)(s + 8);
#pragma unroll
            for (int j = 0; j < 8; j++) {
                Tt[qc * 16 + j][dl] = (unsigned short)a0[j];
                Tt[qc * 16 + 8 + j][dl] = (unsigned short)a1[j];
            }
        } else {
            const float* s = (const float*)src + base;
#pragma unroll
            for (int j = 0; j < 16; j++) Tt[qc * 16 + j][dl] = f2bf(s[j]);
        }
    }
    __syncthreads();
    {
        int el = t >> 2, qc = t & 3;
        size_t dst = (size_t)z * D_ * D_ + (size_t)(c0 * 64 + el) * D_ + r0 + qc * 16;
        *(bf16x8*)&WT[dst]     = *(const bf16x8*)&Tt[el][qc * 16];
        *(bf16x8*)&WT[dst + 8] = *(const bf16x8*)&Tt[el][qc * 16 + 8];
    }
    if (z == 3 && blockIdx.y == 0 && blockIdx.x < 4) {
        const void* bs = (blockIdx.x == 0) ? bq_ : (blockIdx.x == 1) ? bk_
                       : (blockIdx.x == 2) ? bv_ : bo_;
#pragma unroll
        for (int j = 0; j < 4; j++) {
            int i = t * 4 + j;
            biases[blockIdx.x * 1024 + i] = ldin(bs, i, isb);
        }
    }
}

// ---------------------------------------------------------------------------
// Kernel 2: mask bitpack, transposed: packT[b][kt][s] bit k = mask[b][s][kt*64+k]
// ---------------------------------------------------------------------------
__global__ void maskpack(const int* mask, unsigned long long* packT) {
    int W = blockIdx.x * 4 + (threadIdx.x >> 6);    // 0..65535
    int lane = threadIdx.x & 63;
    int b = W >> 14, rem = W & 16383, s = rem >> 4, kt = rem & 15;
    int mv = mask[((size_t)b * 1024 + s) * 1024 + kt * 64 + lane];
    unsigned long long bits = __ballot(mv != 0);
    if (lane == 0) packT[((size_t)b * 16 + kt) * 1024 + s] = bits;
}

// ---------------------------------------------------------------------------
// Kernel 3 (R8): bf16 MFMA GEMM with BN templated. R7 internals kept (DMA
// dbuf, one barrier/iter, XOR-4 swizzle, m-fastest grid). NEW:
//  (1) smaller tiles -> more resident blocks/CU (proj 128x64: 1536 blocks =
//      6/CU; final 64x64: 1024 blocks = 4/CU) — latency is hidden by OTHER
//      blocks' waves, which R4-R7 (3 phased blocks/CU) never had;
//  (2) K-phase rotation: block starts its K sweep at hash(blockIdx)&31 and
//      wraps (sum is order-invariant) -> co-resident blocks' DMA bursts and
//      barrier drains decorrelate.
// MODE 0: 3 projections (z: Q,K -> [b][h][s][e]; V -> [b][h][e][s]).
// MODE 1: final GEMM (A=heads bf16), writes d_out per dtype flag.
// ---------------------------------------------------------------------------
template<int BM, int BN, int MODE, int MINW>
__global__ __launch_bounds__(256, MINW) void gemm_k(
        const void* A0, const void* A1, const void* A2,
        const unsigned short* BtB, const float* biasB, void* dstB, const int* flag) {
    constexpr int TOT16 = (BM + BN) * 32;       // ushorts per buffer
    constexpr int CALLS = TOT16 / 512;          // 1KB chunks (16 rows x 32 cols)
    constexpr int CPW = CALLS / 4;
    constexpr int MT = BM / 32;                 // wave-tile (BM/2)x(BN/2)
    constexpr int NT = BN / 32;
    __shared__ unsigned short buf[2][TOT16];

    const int t = threadIdx.x, lane = t & 63, w = t >> 6;
    const int lm = lane & 15, q4 = lane >> 4;
    const int wm = w >> 1, wn = w & 1;
    const int lr = lane >> 2;                    // row-in-chunk 0..15
    const int ls = lane & 3;                     // LDS slot 0..3
    const int lg = ls ^ ((lr >> 1) & 3);         // source granule (swizzle)
    const int fl = flag[0];

    const void* A; const unsigned short* Bt; const float* bias;
    int aisb, z = 0;
    if (MODE == 0) {
        z = blockIdx.z;
        A = (z == 0) ? A0 : (z == 1 ? A1 : A2);
        Bt = BtB + (size_t)z * D_ * D_;
        bias = biasB + z * 1024;
        aisb = fl;
    } else {
        A = A0; Bt = BtB; bias = biasB; aisb = 1;
    }
    const int m0 = blockIdx.x * BM, n0 = blockIdx.y * BN;   // m fastest (XCD A-dedup)
    const int phase = (blockIdx.x * 7 + blockIdx.y * 13 + blockIdx.z * 5) & 31;

    // stage K-slice kk into buffer bi (swizzled: slot s of row r holds
    // global granule s ^ ((r>>1)&3))
    auto stage = [&](int kk, int bi) {
        if (aisb) {
#pragma unroll
            for (int i = 0; i < CPW; ++i) {
                int c = w * CPW + i;
                int row = c * 16 + lr;
                const unsigned short* g;
                if (row < BM)
                    g = (const unsigned short*)A + (size_t)(m0 + row) * D_ + kk + lg * 8;
                else
                    g = Bt + (size_t)(n0 + row - BM) * D_ + kk + lg * 8;
                gl2lds16(g, &buf[bi][c * 512]);
            }
        } else {
            // fp32 A path: convert via regs into the same swizzled layout
#pragma unroll
            for (int i = 0; i < CPW; ++i) {
                int c = w * CPW + i;
                int row = c * 16 + lr;
                if (row < BM) {
                    const float* af = (const float*)A + (size_t)(m0 + row) * D_ + kk + lg * 8;
                    bf16x8 v;
#pragma unroll
                    for (int jj = 0; jj < 8; jj++) v[jj] = (short)f2bf(af[jj]);
                    *(bf16x8*)(&buf[bi][c * 512 + lane * 8]) = v;
                } else {
                    gl2lds16(Bt + (size_t)(n0 + row - BM) * D_ + kk + lg * 8,
                             &buf[bi][c * 512]);
                }
            }
        }
    };

    f32x4 acc[MT][NT];
#pragma unroll
    for (int i = 0; i < MT; i++)
#pragma unroll
        for (int j = 0; j < NT; j++) acc[i][j] = (f32x4){0.f, 0.f, 0.f, 0.f};

    stage((phase & 31) * 32, 0);
    for (int it = 0; it < D_ / 32; ++it) {
        const int bi = it & 1;
        __syncthreads();                 // drains the prefetch of slice `it`
        if (it < D_ / 32 - 1) stage(((it + 1 + phase) & 31) * 32, bi ^ 1);

        const unsigned short* As = buf[bi];
        const unsigned short* Bs = buf[bi] + BM * 32;
        bf16x8 af[MT], bv[NT];
#pragma unroll
        for (int mt = 0; mt < MT; mt++) {
            int row = wm * (BM / 2) + mt * 16 + lm;
            af[mt] = *(const bf16x8*)&As[row * 32 + (q4 ^ ((row >> 1) & 3)) * 8];
        }
#pragma unroll
        for (int nt = 0; nt < NT; nt++) {
            int row = wn * (BN / 2) + nt * 16 + lm;
            bv[nt] = *(const bf16x8*)&Bs[row * 32 + (q4 ^ ((row >> 1) & 3)) * 8];
        }
#pragma unroll
        for (int mt = 0; mt < MT; mt++)
#pragma unroll
            for (int nt = 0; nt < NT; nt++)
                acc[mt][nt] = __builtin_amdgcn_mfma_f32_16x16x32_bf16(
                    af[mt], bv[nt], acc[mt][nt], 0, 0, 0);
    }

    // epilogue: C/D layout col=lane&15, row=(lane>>4)*4+reg
#pragma unroll
    for (int mt = 0; mt < MT; mt++)
#pragma unroll
        for (int nt = 0; nt < NT; nt++) {
            int N = n0 + wn * (BN / 2) + nt * 16 + lm;
            int Mb = m0 + wm * (BM / 2) + mt * 16 + q4 * 4;
            if (MODE == 0 && z == 2) {
                // V^T: 4 consecutive s per lane -> one b64 store
                int bb = Mb >> 10, sb = Mb & 1023, hh = N >> 6, e = N & 63;
                unsigned long long hv = 0;
#pragma unroll
                for (int r = 0; r < 4; r++)
                    hv |= (unsigned long long)f2bf(acc[mt][nt][r] + bias[N]) << (16 * r);
                unsigned short* d16 = (unsigned short*)dstB + (size_t)2 * BHSE_;
                *(unsigned long long*)&d16[(((size_t)(bb * H_ + hh) * E_ + e) << 10) + sb] = hv;
            } else {
#pragma unroll
                for (int r = 0; r < 4; r++) {
                    int M = Mb + r;
                    float v = acc[mt][nt][r] + bias[N];
                    if (MODE == 0) {
                        int bb = M >> 10, s = M & 1023, hh = N >> 6, e = N & 63;
                        unsigned short* d16 = (unsigned short*)dstB + (size_t)z * BHSE_;
                        d16[((size_t)(bb * H_ + hh) * S_ + s) * E_ + e] = f2bf(v);
                    } else {
                        size_t idx = (size_t)M * D_ + N;
                        if (fl) ((unsigned short*)dstB)[idx] = f2bf(v);
                        else    ((float*)dstB)[idx] = v;
                    }
                }
            }
        }
}

// ---------------------------------------------------------------------------
// Kernel 4: fused attention — R4 config (3-D grid, LDS double-buffered K/V
// DMA tiles, XOR swizzle, base-2 softmax). Unchanged from R6/R7.
// ---------------------------------------------------------------------------
#define PSTR 88
__global__ __launch_bounds__(256) void attn64(
        const unsigned short* Qp, const unsigned short* Kp, const unsigned short* VpT,
        const unsigned long long* packT, unsigned short* heads) {
    __shared__ unsigned short KT[2][4096];   // [buf][64 keys x 64 e], swizzled
    __shared__ unsigned short VT[2][4096];   // [buf][64 e x 64 keys], swizzled
    __shared__ unsigned short Pw[4][16 * PSTR];

    const int qt = blockIdx.x, h = blockIdx.y, b = blockIdx.z;
    const int t = threadIdx.x, w = t >> 6, lane = t & 63, lm = lane & 15, q4 = lane >> 4;
    const size_t bh = ((size_t)b * H_ + h) * S_ * E_;
    const unsigned short* Qb = Qp + bh;
    const unsigned short* Kb = Kp + bh;
    const unsigned short* Vb = VpT + bh;                // Vb[e*1024 + s]
    const int q0 = qt * 64 + w * 16;
    unsigned short* P = &Pw[w][0];

    // per-lane invariant DMA source offsets (ushort units)
    const int l3 = lane >> 3, l7 = lane & 7;
    const int kLaneOff = l3 * 64 + (l7 ^ l3) * 8;       // within an 8-row K chunk
    const int vLaneOff = l3 * 1024 + (l7 ^ l3) * 8;     // within an 8-row V chunk

    // swizzled LDS fragment chunk indices (granule = 8 ushorts)
    const int sw = lm & 7;
    const int c0 = (q4 ^ sw) * 8, c1 = ((q4 ^ 4) ^ sw) * 8;

    // Q B-fragments, held for the whole sweep
    bf16x8 bq0 = *(const bf16x8*)&Qb[(size_t)(q0 + lm) * E_ + q4 * 8];
    bf16x8 bq1 = *(const bf16x8*)&Qb[(size_t)(q0 + lm) * E_ + 32 + q4 * 8];

    f32x4 oacc[4];
#pragma unroll
    for (int i = 0; i < 4; i++) oacc[i] = (f32x4){0.f, 0.f, 0.f, 0.f};
    float mrun = -3.0e38f, lrun = 0.f;
    const float scale2 = 0.03125f * 1.4426950408889634f;   // log2e / sqrt(D)

#define STAGE(ktile, bufi)                                                    \
    {                                                                         \
        int k0s = (ktile) * 64;                                               \
        _Pragma("unroll")                                                     \
        for (int i_ = 0; i_ < 4; ++i_) {                                      \
            int c_ = w * 4 + i_;                                              \
            if (c_ < 8) {                                                     \
                gl2lds16(Kb + (size_t)k0s * 64 + c_ * 512 + kLaneOff,         \
                         &KT[bufi][c_ * 512]);                                \
            } else {                                                          \
                int cc_ = c_ - 8;                                             \
                gl2lds16(Vb + (size_t)cc_ * 8192 + k0s + vLaneOff,            \
                         &VT[bufi][cc_ * 512]);                               \
            }                                                                 \
        }                                                                     \
    }

    STAGE(0, 0)

    for (int kt = 0; kt < S_ / 64; ++kt) {
        const int bufi = kt & 1;
        __syncthreads();                 // own-vmcnt drain + barrier: tile kt ready
        if (kt < 15) STAGE(kt + 1, bufi ^ 1)

        unsigned long long mk = packT[((size_t)b * 16 + kt) * 1024 + q0 + lm];

        // Sc^T from LDS K tile
        f32x4 st[4];
#pragma unroll
        for (int jt = 0; jt < 4; ++jt) {
            const unsigned short* kr = &KT[bufi][(jt * 16 + lm) * 64];
            bf16x8 ka0 = *(const bf16x8*)&kr[c0];
            bf16x8 ka1 = *(const bf16x8*)&kr[c1];
            f32x4 zz = (f32x4){0.f, 0.f, 0.f, 0.f};
            zz = __builtin_amdgcn_mfma_f32_16x16x32_bf16(ka0, bq0, zz, 0, 0, 0);
            zz = __builtin_amdgcn_mfma_f32_16x16x32_bf16(ka1, bq1, zz, 0, 0, 0);
            st[jt] = zz;
        }
        float sv[4][4];
        float tmx = -3.0e38f;
#pragma unroll
        for (int jt = 0; jt < 4; ++jt)
#pragma unroll
            for (int r = 0; r < 4; r++) {
                int kb = jt * 16 + q4 * 4 + r;
                float xm = ((mk >> kb) & 1ull) ? st[jt][r] * scale2 : -3.0e38f;
                sv[jt][r] = xm;
                tmx = fmaxf(tmx, xm);
            }
        tmx = fmaxf(tmx, __shfl_xor(tmx, 16, 64));
        tmx = fmaxf(tmx, __shfl_xor(tmx, 32, 64));
        float mnew = fmaxf(mrun, tmx);
        float alpha = EXP2(mrun - mnew);
        float ssum = 0.f;
        unsigned long long pk[4];
#pragma unroll
        for (int jt = 0; jt < 4; ++jt) {
            float p0 = EXP2(sv[jt][0] - mnew);
            float p1 = EXP2(sv[jt][1] - mnew);
            float p2 = EXP2(sv[jt][2] - mnew);
            float p3 = EXP2(sv[jt][3] - mnew);
            ssum += (p0 + p1) + (p2 + p3);
            pk[jt] = (unsigned long long)f2bf(p0)
                   | ((unsigned long long)f2bf(p1) << 16)
                   | ((unsigned long long)f2bf(p2) << 32)
                   | ((unsigned long long)f2bf(p3) << 48);
        }
        ssum += __shfl_xor(ssum, 16, 64);
        ssum += __shfl_xor(ssum, 32, 64);
        lrun = lrun * alpha + ssum;
        mrun = mnew;
#pragma unroll
        for (int nt = 0; nt < 4; nt++) oacc[nt] = oacc[nt] * alpha;

        // P C->B layout via per-wave LDS (in-order DS pipe, no barrier)
#pragma unroll
        for (int jt = 0; jt < 4; ++jt)
            *(unsigned long long*)&P[lm * PSTR + jt * 16 + q4 * 4] = pk[jt];
        bf16x8 bp0 = *(const bf16x8*)&P[lm * PSTR + q4 * 8];
        bf16x8 bp1 = *(const bf16x8*)&P[lm * PSTR + 32 + q4 * 8];

        // PV from LDS V tile
#pragma unroll
        for (int nt = 0; nt < 4; nt++) {
            const unsigned short* vr = &VT[bufi][(nt * 16 + lm) * 64];
            bf16x8 va0 = *(const bf16x8*)&vr[c0];
            bf16x8 va1 = *(const bf16x8*)&vr[c1];
            oacc[nt] = __builtin_amdgcn_mfma_f32_16x16x32_bf16(va0, bp0, oacc[nt], 0, 0, 0);
            oacc[nt] = __builtin_amdgcn_mfma_f32_16x16x32_bf16(va1, bp1, oacc[nt], 0, 0, 0);
        }
    }

    float inv = 1.0f / lrun;
#pragma unroll
    for (int nt = 0; nt < 4; nt++) {
        unsigned long long hv =
              (unsigned long long)f2bf(oacc[nt][0] * inv)
            | ((unsigned long long)f2bf(oacc[nt][1] * inv) << 16)
            | ((unsigned long long)f2bf(oacc[nt][2] * inv) << 32)
            | ((unsigned long long)f2bf(oacc[nt][3] * inv) << 48);
        *(unsigned long long*)&heads[(size_t)(b * S_ + q0 + lm) * D_ + h * E_ + nt * 16 + q4 * 4] = hv;
    }
}

// ---------------------------------------------------------------------------
extern "C" void kernel_launch(void* const* d_in, const int* in_sizes, int n_in,
                              void* d_out, int out_size, void* d_ws, size_t ws_size,
                              hipStream_t stream) {
    char* ws = (char*)d_ws;
    int* flag = (int*)ws;
    unsigned short* WT = (unsigned short*)(ws + 256);    // [4][1024][1024] bf16
    unsigned short* WqT = WT;
    unsigned short* WoT = WT + (size_t)3 * D_ * D_;
    float* biases = (float*)(WT + (size_t)4 * D_ * D_);  // [4][1024]
    float* bq = biases;
    float* bo = biases + 3 * 1024;
    unsigned short* Qp = (unsigned short*)(biases + 4 * 1024);  // [b][h][s][e]
    unsigned short* Kp = Qp + (size_t)BHSE_;                    // [b][h][s][e]
    unsigned short* Vp = Kp + (size_t)BHSE_;                    // [b][h][e][s]
    unsigned short* heads = Vp + (size_t)BHSE_;                 // [b*s][h*64+e]
    unsigned long long* packT = (unsigned long long*)(heads + (size_t)BHSE_);

    detect_dtype<<<1, 256, 0, stream>>>((const unsigned int*)d_in[0], flag);
    conv_w2<<<dim3(16, 16, 4), 256, 0, stream>>>(
        d_in[4], d_in[6], d_in[8], d_in[10],
        d_in[5], d_in[7], d_in[9], d_in[11], WT, biases, flag);
    maskpack<<<16384, 256, 0, stream>>>((const int*)d_in[3], packT);
    // proj: 128x64 tiles -> 32 x 16 x 3 = 1536 blocks (6/CU)
    gemm_k<128, 64, 0, 4><<<dim3(32, 16, 3), 256, 0, stream>>>(
        d_in[0], d_in[1], d_in[2], WqT, bq, Qp, flag);
    attn64<<<dim3(16, 16, 4), 256, 0, stream>>>(Qp, Kp, Vp, packT, heads);
    // final: 64x64 tiles -> 64 x 16 = 1024 blocks (4/CU), VGPR<=64 forced
    gemm_k<64, 64, 1, 8><<<dim3(64, 16, 1), 256, 0, stream>>>(
        heads, nullptr, nullptr, WoT, bo, d_out, flag);
}